// Round 3
// baseline (202.768 us; speedup 1.0000x reference)
//
#include <hip/hip_runtime.h>
#include <math.h>

// Problem constants (fixed shapes)
#define DIM    4096
#define NH     32
#define NKV    8
#define HD     128
#define BS     16
#define KVLEN  4096
#define LASTPOS 4095
#define QKV_COLS 6144   // 4096 q + 1024 k + 1024 v
#define SS_STR 520      // padded stride for score LDS rows (520%32=8 -> conflict-free)

// ws layout (floats):
//   qkv     : [16][6144]          @ 0        (98304 floats)
//   attn_out: [16][4096]          @ 98304    (65536 floats)
//   partials: [128][8][4][130]    @ 163840   (532480 floats)
#define WS_QKV   0
#define WS_ATTN  98304
#define WS_PART  163840

// ---------------------------------------------------------------------------
// K0: zero qkv (98304 floats) and out (65536 floats) in one dispatch.
// 160 blocks x 256 threads x float4 = 40960 float4 = 163840 floats.
// ---------------------------------------------------------------------------
__global__ __launch_bounds__(256) void zero_ws(
    float* __restrict__ qkv, float* __restrict__ out) {
  int i = blockIdx.x * 256 + threadIdx.x;
  float4 z = make_float4(0.f, 0.f, 0.f, 0.f);
  if (i < 24576) ((float4*)qkv)[i] = z;
  else           ((float4*)out)[i - 24576] = z;
}

// ---------------------------------------------------------------------------
// K1: qkv = x @ [wq|wk|wv], split-K (64-row chunks) with fp32 atomics.
// block: 256 threads, 2 cols/thread (512 cols/block); grid (12, 64) = 768 blocks
// ---------------------------------------------------------------------------
__global__ __launch_bounds__(256) void qkv_proj(
    const float* __restrict__ x, const float* __restrict__ wq,
    const float* __restrict__ wk, const float* __restrict__ wv,
    float* __restrict__ qkv) {
  __shared__ float xs[16 * 64];
  const int tid = threadIdx.x;
  const int col = (blockIdx.x * 256 + tid) * 2;   // 0..6142, block-uniform matrix
  const int k0 = blockIdx.y * 64;

  for (int i = tid; i < 1024; i += 256) {
    int b = i >> 6, k = i & 63;
    xs[i] = x[b * DIM + k0 + k];
  }
  __syncthreads();

  const float* w;
  int wstride, wcol;
  if (col < 4096)      { w = wq; wstride = 4096; wcol = col; }
  else if (col < 5120) { w = wk; wstride = 1024; wcol = col - 4096; }
  else                 { w = wv; wstride = 1024; wcol = col - 5120; }
  const float* wp = w + (size_t)k0 * wstride + wcol;

  float acc0[16], acc1[16];
#pragma unroll
  for (int b = 0; b < 16; ++b) { acc0[b] = 0.f; acc1[b] = 0.f; }

#pragma unroll 2
  for (int k = 0; k < 64; k += 4) {
    float2 w0 = *(const float2*)(wp + (size_t)(k + 0) * wstride);
    float2 w1 = *(const float2*)(wp + (size_t)(k + 1) * wstride);
    float2 w2 = *(const float2*)(wp + (size_t)(k + 2) * wstride);
    float2 w3 = *(const float2*)(wp + (size_t)(k + 3) * wstride);
#pragma unroll
    for (int b = 0; b < 16; ++b) {
      float4 xb = *(const float4*)(&xs[b * 64 + k]);
      acc0[b] += xb.x * w0.x + xb.y * w1.x + xb.z * w2.x + xb.w * w3.x;
      acc1[b] += xb.x * w0.y + xb.y * w1.y + xb.z * w2.y + xb.w * w3.y;
    }
  }
#pragma unroll
  for (int b = 0; b < 16; ++b) {
    atomicAdd(&qkv[b * QKV_COLS + col],     acc0[b]);
    atomicAdd(&qkv[b * QKV_COLS + col + 1], acc1[b]);
  }
}

// ---------------------------------------------------------------------------
// K2: RoPE on q (scaled by 1/sqrt(HD)) and k, in place in qkv buffer.
// ---------------------------------------------------------------------------
__global__ __launch_bounds__(256) void rope_kernel(
    float* __restrict__ qkv, const float* __restrict__ fc,
    const float* __restrict__ fs) {
  int t = blockIdx.x * 256 + threadIdx.x;
  if (t >= 16 * 40 * 64) return;
  int i  = t & 63;
  int hh = (t >> 6) % 40;
  int b  = t / (40 * 64);
  float c = fc[i], s = fs[i];
  int base;
  float scale;
  if (hh < 32) { base = b * QKV_COLS + hh * 128 + 2 * i; scale = 0.08838834764831845f; }
  else         { base = b * QKV_COLS + 4096 + (hh - 32) * 128 + 2 * i; scale = 1.0f; }
  float e = qkv[base], o = qkv[base + 1];
  qkv[base]     = (e * c - o * s) * scale;
  qkv[base + 1] = (e * s + o * c) * scale;
}

// ---------------------------------------------------------------------------
// K3: attention partials. block = (b, g, chunk of 512 kv positions).
// 512 threads = 8 waves.
// Scores: 16-lane groups own one K row (4 rows/wave/iter), lane holds 8 d,
//         4-deep shfl_xor reduce. Wave w covers rows [w*64, w*64+64).
// Softmax: waves 0-3, head = wave id (chunk-local partial).
// PV: wave w covers rows [w*64, w*64+64) for ALL 4 heads; half-wave owns a
//     row, lane loads float4 (16B), 2 rows/iter, unroll 2; shfl_xor(32)
//     combine; cross-wave combine through LDS.
// ---------------------------------------------------------------------------
__global__ __launch_bounds__(512, 4) void attn_partial(
    const float* __restrict__ cache_k, const float* __restrict__ cache_v,
    const float* __restrict__ qkv, float* __restrict__ part) {
  __shared__ float qs[512];
  __shared__ float ss[4 * SS_STR];
  __shared__ float pacc[8][4][128];
  const int tid = threadIdx.x;
  const int w = tid >> 6, lane = tid & 63;
  const int p = lane >> 4, ql = lane & 15;
  const int chunk = blockIdx.x & 7;
  const int bg = blockIdx.x >> 3;
  const int b = bg >> 3, g = bg & 7;

  qs[tid] = qkv[b * QKV_COLS + g * 512 + tid];
  __syncthreads();

  // Q fragments: head h, d-range [ql*8, ql*8+8)
  float4 qA[4], qB[4];
#pragma unroll
  for (int h = 0; h < 4; ++h) {
    qA[h] = *(const float4*)(&qs[h * 128 + ql * 8]);
    qB[h] = *(const float4*)(&qs[h * 128 + ql * 8 + 4]);
  }

  const int t0 = chunk * 512;
  const float* kbase = cache_k + ((size_t)b * 4096 * 8 + g) * 128;
  const float* xk    = qkv + b * QKV_COLS + 4096 + g * 128;

  // ---- scores ----
  for (int it = 0; it < 16; ++it) {
    int r = w * 64 + it * 4 + p;
    int t = t0 + r;
    const float* krow = (t == LASTPOS) ? xk : (kbase + (size_t)t * 1024);
    float4 k0 = *(const float4*)(krow + ql * 8);
    float4 k1 = *(const float4*)(krow + ql * 8 + 4);
    float s[4];
#pragma unroll
    for (int h = 0; h < 4; ++h) {
      s[h] = k0.x * qA[h].x + k0.y * qA[h].y + k0.z * qA[h].z + k0.w * qA[h].w
           + k1.x * qB[h].x + k1.y * qB[h].y + k1.z * qB[h].z + k1.w * qB[h].w;
    }
#pragma unroll
    for (int off = 1; off < 16; off <<= 1) {
#pragma unroll
      for (int h = 0; h < 4; ++h) s[h] += __shfl_xor(s[h], off);
    }
    float v = (ql == 0) ? s[0] : (ql == 1) ? s[1] : (ql == 2) ? s[2] : s[3];
    if (ql < 4) ss[ql * SS_STR + r] = v;
  }
  __syncthreads();

  // ---- chunk-local softmax, head = wave (waves 0-3) ----
  float* prow = part + ((size_t)(bg * 8 + chunk) * 4 + (w & 3)) * 130;
  if (w < 4) {
    float vals[8];
    float m = -1e30f;
#pragma unroll
    for (int i = 0; i < 8; ++i) {
      vals[i] = ss[w * SS_STR + lane + 64 * i];
      m = fmaxf(m, vals[i]);
    }
#pragma unroll
    for (int off = 1; off < 64; off <<= 1) m = fmaxf(m, __shfl_xor(m, off));
    float l = 0.f;
#pragma unroll
    for (int i = 0; i < 8; ++i) {
      float pe = __expf(vals[i] - m);
      ss[w * SS_STR + lane + 64 * i] = pe;
      l += pe;
    }
#pragma unroll
    for (int off = 1; off < 64; off <<= 1) l += __shfl_xor(l, off);
    if (lane == 0) { prow[128] = m; prow[129] = l; }
  }
  __syncthreads();

  // ---- PV: wave w covers rows [w*64, w*64+64), half-wave owns a row ----
  const float* vbase = cache_v + ((size_t)b * 4096 * 8 + g) * 128;
  const float* xv    = qkv + b * QKV_COLS + 5120 + g * 128;
  const int h2 = lane >> 5;      // which of the 2 rows per iteration
  const int dq = lane & 31;      // d-quad: covers d = dq*4 .. dq*4+3
  float4 acc[4];
#pragma unroll
  for (int h = 0; h < 4; ++h) acc[h] = make_float4(0.f, 0.f, 0.f, 0.f);

#pragma unroll 2
  for (int j = 0; j < 32; ++j) {
    int r = w * 64 + 2 * j + h2;
    int t = t0 + r;
    const float* vrow = (t == LASTPOS) ? xv : (vbase + (size_t)t * 1024);
    float4 vv = *(const float4*)(vrow + dq * 4);
    float p0 = ss[0 * SS_STR + r];
    float p1 = ss[1 * SS_STR + r];
    float p2 = ss[2 * SS_STR + r];
    float p3 = ss[3 * SS_STR + r];
    acc[0].x += p0 * vv.x; acc[0].y += p0 * vv.y; acc[0].z += p0 * vv.z; acc[0].w += p0 * vv.w;
    acc[1].x += p1 * vv.x; acc[1].y += p1 * vv.y; acc[1].z += p1 * vv.z; acc[1].w += p1 * vv.w;
    acc[2].x += p2 * vv.x; acc[2].y += p2 * vv.y; acc[2].z += p2 * vv.z; acc[2].w += p2 * vv.w;
    acc[3].x += p3 * vv.x; acc[3].y += p3 * vv.y; acc[3].z += p3 * vv.z; acc[3].w += p3 * vv.w;
  }
#pragma unroll
  for (int h = 0; h < 4; ++h) {
    acc[h].x += __shfl_xor(acc[h].x, 32);
    acc[h].y += __shfl_xor(acc[h].y, 32);
    acc[h].z += __shfl_xor(acc[h].z, 32);
    acc[h].w += __shfl_xor(acc[h].w, 32);
  }
  if (lane < 32) {
#pragma unroll
    for (int h = 0; h < 4; ++h)
      *(float4*)(&pacc[w][h][dq * 4]) = acc[h];
  }
  __syncthreads();

  // ---- cross-wave combine: 512 threads = 4 heads x 128 d ----
  {
    int h = tid >> 7, d = tid & 127;
    float sum = 0.f;
#pragma unroll
    for (int w2 = 0; w2 < 8; ++w2) sum += pacc[w2][h][d];
    part[((size_t)(bg * 8 + chunk) * 4 + h) * 130 + d] = sum;
  }
}

// ---------------------------------------------------------------------------
// K4: combine 8 chunk-partials per (b,g,r,d) -> attn_out[b][h][d]
// ---------------------------------------------------------------------------
__global__ __launch_bounds__(256) void attn_combine(
    const float* __restrict__ part, float* __restrict__ attn_out) {
  int t = blockIdx.x * 256 + threadIdx.x;  // 65536
  int d = t & 127, r = (t >> 7) & 3, bg = t >> 9;
  int b = bg >> 3, g = bg & 7;
  float ms[8];
  float M = -1e30f;
#pragma unroll
  for (int c = 0; c < 8; ++c) {
    ms[c] = part[((size_t)(bg * 8 + c) * 4 + r) * 130 + 128];
    M = fmaxf(M, ms[c]);
  }
  float num = 0.f, den = 0.f;
#pragma unroll
  for (int c = 0; c < 8; ++c) {
    const float* prow = part + ((size_t)(bg * 8 + c) * 4 + r) * 130;
    float wgt = __expf(ms[c] - M);
    num += wgt * prow[d];
    den += wgt * prow[129];
  }
  attn_out[b * DIM + (g * 4 + r) * 128 + d] = num / den;
}

// ---------------------------------------------------------------------------
// K5: out = attn_out @ wo, split-K (64-row chunks) with fp32 atomics.
// block: 256 threads, 1 col/thread; grid (16, 64) = 1024 blocks.
// ---------------------------------------------------------------------------
__global__ __launch_bounds__(256) void out_proj(
    const float* __restrict__ attn, const float* __restrict__ wo,
    float* __restrict__ out) {
  __shared__ float xs[16 * 64];
  const int tid = threadIdx.x;
  const int col = blockIdx.x * 256 + tid;  // 0..4095
  const int k0 = blockIdx.y * 64;

  for (int i = tid; i < 1024; i += 256) {
    int b = i >> 6, k = i & 63;
    xs[i] = attn[b * DIM + k0 + k];
  }
  __syncthreads();

  const float* wp = wo + (size_t)k0 * 4096 + col;
  float acc[16];
#pragma unroll
  for (int b = 0; b < 16; ++b) acc[b] = 0.f;

#pragma unroll 2
  for (int k = 0; k < 64; k += 4) {
    float w0 = wp[(size_t)(k + 0) * 4096];
    float w1 = wp[(size_t)(k + 1) * 4096];
    float w2 = wp[(size_t)(k + 2) * 4096];
    float w3 = wp[(size_t)(k + 3) * 4096];
#pragma unroll
    for (int b = 0; b < 16; ++b) {
      float4 xb = *(const float4*)(&xs[b * 64 + k]);
      acc[b] += xb.x * w0 + xb.y * w1 + xb.z * w2 + xb.w * w3;
    }
  }
#pragma unroll
  for (int b = 0; b < 16; ++b) atomicAdd(&out[b * DIM + col], acc[b]);
}

// ---------------------------------------------------------------------------
extern "C" void kernel_launch(void* const* d_in, const int* in_sizes, int n_in,
                              void* d_out, int out_size, void* d_ws, size_t ws_size,
                              hipStream_t stream) {
  const float* x  = (const float*)d_in[0];
  const float* wq = (const float*)d_in[1];
  const float* wk = (const float*)d_in[2];
  const float* wv = (const float*)d_in[3];
  const float* wo = (const float*)d_in[4];
  const float* ck = (const float*)d_in[5];
  const float* cv = (const float*)d_in[6];
  const float* fc = (const float*)d_in[7];
  const float* fs = (const float*)d_in[8];

  float* ws_f  = (float*)d_ws;
  float* qkv   = ws_f + WS_QKV;
  float* attn  = ws_f + WS_ATTN;
  float* part  = ws_f + WS_PART;
  float* out   = (float*)d_out;

  zero_ws<<<160, 256, 0, stream>>>(qkv, out);
  qkv_proj<<<dim3(12, 64), 256, 0, stream>>>(x, wq, wk, wv, qkv);
  rope_kernel<<<160, 256, 0, stream>>>(qkv, fc, fs);
  attn_partial<<<1024, 512, 0, stream>>>(ck, cv, qkv, part);
  attn_combine<<<256, 256, 0, stream>>>(part, attn);
  out_proj<<<dim3(16, 64), 256, 0, stream>>>(attn, wo, out);
}

// Round 4
// 185.395 us; speedup vs baseline: 1.0937x; 1.0937x over previous
//
#include <hip/hip_runtime.h>
#include <math.h>

// Problem constants (fixed shapes)
#define DIM    4096
#define NH     32
#define NKV    8
#define HD     128
#define BS     16
#define KVLEN  4096
#define LASTPOS 4095
#define QKV_COLS 6144   // 4096 q + 1024 k + 1024 v
#define CHUNK  256      // kv rows per attn block
#define NCH    16       // number of kv chunks
#define SS_STR 264      // padded score-row stride (264%32==8)
#define NKC    64       // k-chunks for split-K projections

// ws layout (floats):
//   qkv       : [16][6144]               @ 0         (98304)
//   attn_out  : [16][4096]               @ 98304     (65536)
//   part      : [128][16][4][130]        @ 163840    (1064960)
//   pq (qkvA) : [64][16][6144]           @ 1228800   (6291456)
//   pw (woA)  : [64][16][4096]           @ 7520256   (4194304)  end 11714560 (~47MB)
#define WS_QKV   0
#define WS_ATTN  98304
#define WS_PART  163840
#define WS_PQ    1228800
#define WS_PW    7520256

// ---------------------------------------------------------------------------
// K1a: qkv partials. block: 256 thr, 2 cols/thread (512 cols); grid (12, 64).
// partial[kc][b][col] written coalesced, no atomics.
// ---------------------------------------------------------------------------
__global__ __launch_bounds__(256) void qkv_projA(
    const float* __restrict__ x, const float* __restrict__ wq,
    const float* __restrict__ wk, const float* __restrict__ wv,
    float* __restrict__ pq) {
  __shared__ float xs[16 * 64];
  const int tid = threadIdx.x;
  const int col = (blockIdx.x * 256 + tid) * 2;   // block-uniform matrix select
  const int kc = blockIdx.y;
  const int k0 = kc * 64;

  for (int i = tid; i < 1024; i += 256) {
    int b = i >> 6, k = i & 63;
    xs[i] = x[b * DIM + k0 + k];
  }
  __syncthreads();

  const float* w;
  int wstride, wcol;
  if (col < 4096)      { w = wq; wstride = 4096; wcol = col; }
  else if (col < 5120) { w = wk; wstride = 1024; wcol = col - 4096; }
  else                 { w = wv; wstride = 1024; wcol = col - 5120; }
  const float* wp = w + (size_t)k0 * wstride + wcol;

  float acc0[16], acc1[16];
#pragma unroll
  for (int b = 0; b < 16; ++b) { acc0[b] = 0.f; acc1[b] = 0.f; }

#pragma unroll 2
  for (int k = 0; k < 64; k += 4) {
    float2 w0 = *(const float2*)(wp + (size_t)(k + 0) * wstride);
    float2 w1 = *(const float2*)(wp + (size_t)(k + 1) * wstride);
    float2 w2 = *(const float2*)(wp + (size_t)(k + 2) * wstride);
    float2 w3 = *(const float2*)(wp + (size_t)(k + 3) * wstride);
#pragma unroll
    for (int b = 0; b < 16; ++b) {
      float4 xb = *(const float4*)(&xs[b * 64 + k]);
      acc0[b] += xb.x * w0.x + xb.y * w1.x + xb.z * w2.x + xb.w * w3.x;
      acc1[b] += xb.x * w0.y + xb.y * w1.y + xb.z * w2.y + xb.w * w3.y;
    }
  }
#pragma unroll
  for (int b = 0; b < 16; ++b) {
    *(float2*)(&pq[((size_t)kc * 16 + b) * QKV_COLS + col]) = make_float2(acc0[b], acc1[b]);
  }
}

// ---------------------------------------------------------------------------
// K1b: reduce 64 qkv partials + fused RoPE (+ q scale). One thread per
// (b, col-pair). 49152 threads = 192 blocks.
// ---------------------------------------------------------------------------
__global__ __launch_bounds__(256) void qkv_projB(
    const float* __restrict__ pq, float* __restrict__ qkv,
    const float* __restrict__ fc, const float* __restrict__ fs) {
  int t = blockIdx.x * 256 + threadIdx.x;       // 0..49151
  int b = t / 3072, pr = t % 3072;
  int col = 2 * pr;
  float e = 0.f, o = 0.f;
#pragma unroll 8
  for (int kc = 0; kc < NKC; ++kc) {
    float2 v = *(const float2*)(&pq[((size_t)kc * 16 + b) * QKV_COLS + col]);
    e += v.x; o += v.y;
  }
  float re = e, im = o;
  if (col < 5120) {  // q or k: rope
    int i = (col & 127) >> 1;
    float c = fc[i], s = fs[i];
    float scale = (col < 4096) ? 0.08838834764831845f : 1.0f;
    re = (e * c - o * s) * scale;
    im = (e * s + o * c) * scale;
  }
  *(float2*)(&qkv[b * QKV_COLS + col]) = make_float2(re, im);
}

// ---------------------------------------------------------------------------
// K3: attention partials. block = (b, g, chunk of 256 kv rows), 512 thr = 8 waves.
// Scores: 16-lane groups own a K row (4 rows/wave/iter), lane holds 8 d,
//         4-deep shfl_xor reduce. Wave w covers rows [w*32, w*32+32).
// Softmax: waves 0-3, head = wave id (chunk-local partial).
// PV: wave w covers rows [w*32, w*32+32) for ALL 4 heads; half-wave owns a
//     row, lane loads float4, unroll 4; shfl_xor(32) + LDS cross-wave combine.
// ---------------------------------------------------------------------------
__global__ __launch_bounds__(512, 8) void attn_partial(
    const float* __restrict__ cache_k, const float* __restrict__ cache_v,
    const float* __restrict__ qkv, float* __restrict__ part) {
  __shared__ float qs[512];
  __shared__ float ss[4 * SS_STR];
  __shared__ float pacc[8][4][128];
  const int tid = threadIdx.x;
  const int w = tid >> 6, lane = tid & 63;
  const int p = lane >> 4, ql = lane & 15;
  const int chunk = blockIdx.x & 15;
  const int bg = blockIdx.x >> 4;
  const int b = bg >> 3, g = bg & 7;

  qs[tid] = qkv[b * QKV_COLS + g * 512 + tid];
  __syncthreads();

  // Q fragments: head h, d-range [ql*8, ql*8+8)
  float4 qA[4], qB[4];
#pragma unroll
  for (int h = 0; h < 4; ++h) {
    qA[h] = *(const float4*)(&qs[h * 128 + ql * 8]);
    qB[h] = *(const float4*)(&qs[h * 128 + ql * 8 + 4]);
  }

  const int t0 = chunk * CHUNK;
  const float* kbase = cache_k + ((size_t)b * 4096 * 8 + g) * 128;
  const float* xk    = qkv + b * QKV_COLS + 4096 + g * 128;

  // ---- scores ----
#pragma unroll 1
  for (int it = 0; it < 8; ++it) {
    int r = w * 32 + it * 4 + p;
    int t = t0 + r;
    const float* krow = (t == LASTPOS) ? xk : (kbase + (size_t)t * 1024);
    float4 k0 = *(const float4*)(krow + ql * 8);
    float4 k1 = *(const float4*)(krow + ql * 8 + 4);
    float s[4];
#pragma unroll
    for (int h = 0; h < 4; ++h) {
      s[h] = k0.x * qA[h].x + k0.y * qA[h].y + k0.z * qA[h].z + k0.w * qA[h].w
           + k1.x * qB[h].x + k1.y * qB[h].y + k1.z * qB[h].z + k1.w * qB[h].w;
    }
#pragma unroll
    for (int off = 1; off < 16; off <<= 1) {
#pragma unroll
      for (int h = 0; h < 4; ++h) s[h] += __shfl_xor(s[h], off);
    }
    float v = (ql == 0) ? s[0] : (ql == 1) ? s[1] : (ql == 2) ? s[2] : s[3];
    if (ql < 4) ss[ql * SS_STR + r] = v;
  }
  __syncthreads();

  // ---- chunk-local softmax, head = wave (waves 0-3) ----
  float* prow = part + ((size_t)(bg * NCH + chunk) * 4 + (w & 3)) * 130;
  if (w < 4) {
    float vals[4];
    float m = -1e30f;
#pragma unroll
    for (int i = 0; i < 4; ++i) {
      vals[i] = ss[w * SS_STR + lane + 64 * i];
      m = fmaxf(m, vals[i]);
    }
#pragma unroll
    for (int off = 1; off < 64; off <<= 1) m = fmaxf(m, __shfl_xor(m, off));
    float l = 0.f;
#pragma unroll
    for (int i = 0; i < 4; ++i) {
      float pe = __expf(vals[i] - m);
      ss[w * SS_STR + lane + 64 * i] = pe;
      l += pe;
    }
#pragma unroll
    for (int off = 1; off < 64; off <<= 1) l += __shfl_xor(l, off);
    if (lane == 0) { prow[128] = m; prow[129] = l; }
  }
  __syncthreads();

  // ---- PV: wave w covers rows [w*32, w*32+32), half-wave owns a row ----
  const float* vbase = cache_v + ((size_t)b * 4096 * 8 + g) * 128;
  const float* xv    = qkv + b * QKV_COLS + 5120 + g * 128;
  const int h2 = lane >> 5;
  const int dq = lane & 31;
  float4 acc[4];
#pragma unroll
  for (int h = 0; h < 4; ++h) acc[h] = make_float4(0.f, 0.f, 0.f, 0.f);

#pragma unroll 4
  for (int j = 0; j < 16; ++j) {
    int r = w * 32 + 2 * j + h2;
    int t = t0 + r;
    const float* vrow = (t == LASTPOS) ? xv : (vbase + (size_t)t * 1024);
    float4 vv = *(const float4*)(vrow + dq * 4);
    float p0 = ss[0 * SS_STR + r];
    float p1 = ss[1 * SS_STR + r];
    float p2 = ss[2 * SS_STR + r];
    float p3 = ss[3 * SS_STR + r];
    acc[0].x += p0 * vv.x; acc[0].y += p0 * vv.y; acc[0].z += p0 * vv.z; acc[0].w += p0 * vv.w;
    acc[1].x += p1 * vv.x; acc[1].y += p1 * vv.y; acc[1].z += p1 * vv.z; acc[1].w += p1 * vv.w;
    acc[2].x += p2 * vv.x; acc[2].y += p2 * vv.y; acc[2].z += p2 * vv.z; acc[2].w += p2 * vv.w;
    acc[3].x += p3 * vv.x; acc[3].y += p3 * vv.y; acc[3].z += p3 * vv.z; acc[3].w += p3 * vv.w;
  }
#pragma unroll
  for (int h = 0; h < 4; ++h) {
    acc[h].x += __shfl_xor(acc[h].x, 32);
    acc[h].y += __shfl_xor(acc[h].y, 32);
    acc[h].z += __shfl_xor(acc[h].z, 32);
    acc[h].w += __shfl_xor(acc[h].w, 32);
  }
  if (lane < 32) {
#pragma unroll
    for (int h = 0; h < 4; ++h)
      *(float4*)(&pacc[w][h][dq * 4]) = acc[h];
  }
  __syncthreads();

  // ---- cross-wave combine: 512 threads = 4 heads x 128 d ----
  {
    int h = tid >> 7, d = tid & 127;
    float sum = 0.f;
#pragma unroll
    for (int w2 = 0; w2 < 8; ++w2) sum += pacc[w2][h][d];
    part[((size_t)(bg * NCH + chunk) * 4 + h) * 130 + d] = sum;
  }
}

// ---------------------------------------------------------------------------
// K4: combine 16 chunk-partials per (b,g,r,d) -> attn_out[b][h][d]
// ---------------------------------------------------------------------------
__global__ __launch_bounds__(256) void attn_combine(
    const float* __restrict__ part, float* __restrict__ attn_out) {
  int t = blockIdx.x * 256 + threadIdx.x;  // 65536
  int d = t & 127, r = (t >> 7) & 3, bg = t >> 9;
  int b = bg >> 3, g = bg & 7;
  float M = -1e30f;
  float ms[NCH];
#pragma unroll
  for (int c = 0; c < NCH; ++c) {
    ms[c] = part[((size_t)(bg * NCH + c) * 4 + r) * 130 + 128];
    M = fmaxf(M, ms[c]);
  }
  float num = 0.f, den = 0.f;
#pragma unroll
  for (int c = 0; c < NCH; ++c) {
    const float* prow = part + ((size_t)(bg * NCH + c) * 4 + r) * 130;
    float wgt = __expf(ms[c] - M);
    num += wgt * prow[d];
    den += wgt * prow[129];
  }
  attn_out[b * DIM + (g * 4 + r) * 128 + d] = num / den;
}

// ---------------------------------------------------------------------------
// K5a: wo partials. block: 256 thr, 2 cols/thread (512 cols); grid (8, 64).
// ---------------------------------------------------------------------------
__global__ __launch_bounds__(256) void out_projA(
    const float* __restrict__ attn, const float* __restrict__ wo,
    float* __restrict__ pw) {
  __shared__ float xs[16 * 64];
  const int tid = threadIdx.x;
  const int col = (blockIdx.x * 256 + tid) * 2;  // 0..4094
  const int kc = blockIdx.y;
  const int k0 = kc * 64;

  for (int i = tid; i < 1024; i += 256) {
    int b = i >> 6, k = i & 63;
    xs[i] = attn[b * DIM + k0 + k];
  }
  __syncthreads();

  const float* wp = wo + (size_t)k0 * 4096 + col;
  float acc0[16], acc1[16];
#pragma unroll
  for (int b = 0; b < 16; ++b) { acc0[b] = 0.f; acc1[b] = 0.f; }

#pragma unroll 2
  for (int k = 0; k < 64; k += 4) {
    float2 w0 = *(const float2*)(wp + (size_t)(k + 0) * 4096);
    float2 w1 = *(const float2*)(wp + (size_t)(k + 1) * 4096);
    float2 w2 = *(const float2*)(wp + (size_t)(k + 2) * 4096);
    float2 w3 = *(const float2*)(wp + (size_t)(k + 3) * 4096);
#pragma unroll
    for (int b = 0; b < 16; ++b) {
      float4 xb = *(const float4*)(&xs[b * 64 + k]);
      acc0[b] += xb.x * w0.x + xb.y * w1.x + xb.z * w2.x + xb.w * w3.x;
      acc1[b] += xb.x * w0.y + xb.y * w1.y + xb.z * w2.y + xb.w * w3.y;
    }
  }
#pragma unroll
  for (int b = 0; b < 16; ++b) {
    *(float2*)(&pw[((size_t)kc * 16 + b) * DIM + col]) = make_float2(acc0[b], acc1[b]);
  }
}

// ---------------------------------------------------------------------------
// K5b: reduce 64 wo partials -> d_out. One thread per (b, col). 256 blocks.
// ---------------------------------------------------------------------------
__global__ __launch_bounds__(256) void out_projB(
    const float* __restrict__ pw, float* __restrict__ out) {
  int t = blockIdx.x * 256 + threadIdx.x;  // 65536
  int b = t >> 12, col = t & 4095;
  float sum = 0.f;
#pragma unroll 8
  for (int kc = 0; kc < NKC; ++kc)
    sum += pw[((size_t)kc * 16 + b) * DIM + col];
  out[b * DIM + col] = sum;
}

// ---------------------------------------------------------------------------
extern "C" void kernel_launch(void* const* d_in, const int* in_sizes, int n_in,
                              void* d_out, int out_size, void* d_ws, size_t ws_size,
                              hipStream_t stream) {
  const float* x  = (const float*)d_in[0];
  const float* wq = (const float*)d_in[1];
  const float* wk = (const float*)d_in[2];
  const float* wv = (const float*)d_in[3];
  const float* wo = (const float*)d_in[4];
  const float* ck = (const float*)d_in[5];
  const float* cv = (const float*)d_in[6];
  const float* fc = (const float*)d_in[7];
  const float* fs = (const float*)d_in[8];

  float* ws_f  = (float*)d_ws;
  float* qkv   = ws_f + WS_QKV;
  float* attn  = ws_f + WS_ATTN;
  float* part  = ws_f + WS_PART;
  float* pq    = ws_f + WS_PQ;
  float* pw    = ws_f + WS_PW;
  float* out   = (float*)d_out;

  qkv_projA<<<dim3(12, NKC), 256, 0, stream>>>(x, wq, wk, wv, pq);
  qkv_projB<<<192, 256, 0, stream>>>(pq, qkv, fc, fs);
  attn_partial<<<2048, 512, 0, stream>>>(ck, cv, qkv, part);
  attn_combine<<<256, 256, 0, stream>>>(part, attn);
  out_projA<<<dim3(8, NKC), 256, 0, stream>>>(attn, wo, pw);
  out_projB<<<256, 256, 0, stream>>>(pw, out);
}

// Round 5
// 184.907 us; speedup vs baseline: 1.0966x; 1.0026x over previous
//
#include <hip/hip_runtime.h>
#include <math.h>

// Problem constants (fixed shapes)
#define DIM    4096
#define NH     32
#define NKV    8
#define HD     128
#define BS     16
#define KVLEN  4096
#define LASTPOS 4095
#define QKV_COLS 6144   // 4096 q + 1024 k + 1024 v
#define CHUNK  256      // kv rows per attn block
#define NCH    16       // number of kv chunks
#define SS_STR 264      // padded score-row stride (264%32==8)
#define NKC    64       // k-chunks for split-K projections

// ws layout (floats):
//   qkv       : [16][6144]               @ 0         (98304)
//   attn_out  : [16][4096]               @ 98304     (65536)
//   part      : [128][16][4][130]        @ 163840    (1064960)
//   pq (qkvA) : [64][16][6144]           @ 1228800   (6291456)
//   pw (woA)  : [64][16][4096]           @ 7520256   (4194304)  end 11714560 (~47MB)
#define WS_QKV   0
#define WS_ATTN  98304
#define WS_PART  163840
#define WS_PQ    1228800
#define WS_PW    7520256

// ---------------------------------------------------------------------------
// K1a: qkv partials. block: 256 thr, 2 cols/thread (512 cols); grid (12, 64).
// ---------------------------------------------------------------------------
__global__ __launch_bounds__(256) void qkv_projA(
    const float* __restrict__ x, const float* __restrict__ wq,
    const float* __restrict__ wk, const float* __restrict__ wv,
    float* __restrict__ pq) {
  __shared__ float xs[16 * 64];
  const int tid = threadIdx.x;
  const int col = (blockIdx.x * 256 + tid) * 2;   // block-uniform matrix select
  const int kc = blockIdx.y;
  const int k0 = kc * 64;

  for (int i = tid; i < 1024; i += 256) {
    int b = i >> 6, k = i & 63;
    xs[i] = x[b * DIM + k0 + k];
  }
  __syncthreads();

  const float* w;
  int wstride, wcol;
  if (col < 4096)      { w = wq; wstride = 4096; wcol = col; }
  else if (col < 5120) { w = wk; wstride = 1024; wcol = col - 4096; }
  else                 { w = wv; wstride = 1024; wcol = col - 5120; }
  const float* wp = w + (size_t)k0 * wstride + wcol;

  float acc0[16], acc1[16];
#pragma unroll
  for (int b = 0; b < 16; ++b) { acc0[b] = 0.f; acc1[b] = 0.f; }

#pragma unroll 2
  for (int k = 0; k < 64; k += 4) {
    float2 w0 = *(const float2*)(wp + (size_t)(k + 0) * wstride);
    float2 w1 = *(const float2*)(wp + (size_t)(k + 1) * wstride);
    float2 w2 = *(const float2*)(wp + (size_t)(k + 2) * wstride);
    float2 w3 = *(const float2*)(wp + (size_t)(k + 3) * wstride);
#pragma unroll
    for (int b = 0; b < 16; ++b) {
      float4 xb = *(const float4*)(&xs[b * 64 + k]);
      acc0[b] += xb.x * w0.x + xb.y * w1.x + xb.z * w2.x + xb.w * w3.x;
      acc1[b] += xb.x * w0.y + xb.y * w1.y + xb.z * w2.y + xb.w * w3.y;
    }
  }
#pragma unroll
  for (int b = 0; b < 16; ++b) {
    *(float2*)(&pq[((size_t)kc * 16 + b) * QKV_COLS + col]) = make_float2(acc0[b], acc1[b]);
  }
}

// ---------------------------------------------------------------------------
// K1b: reduce 64 qkv partials + fused RoPE (+ q scale).
// ---------------------------------------------------------------------------
__global__ __launch_bounds__(256) void qkv_projB(
    const float* __restrict__ pq, float* __restrict__ qkv,
    const float* __restrict__ fc, const float* __restrict__ fs) {
  int t = blockIdx.x * 256 + threadIdx.x;       // 0..49151
  int b = t / 3072, pr = t % 3072;
  int col = 2 * pr;
  float e = 0.f, o = 0.f;
#pragma unroll 8
  for (int kc = 0; kc < NKC; ++kc) {
    float2 v = *(const float2*)(&pq[((size_t)kc * 16 + b) * QKV_COLS + col]);
    e += v.x; o += v.y;
  }
  float re = e, im = o;
  if (col < 5120) {  // q or k: rope
    int i = (col & 127) >> 1;
    float c = fc[i], s = fs[i];
    float scale = (col < 4096) ? 0.08838834764831845f : 1.0f;
    re = (e * c - o * s) * scale;
    im = (e * s + o * c) * scale;
  }
  *(float2*)(&qkv[b * QKV_COLS + col]) = make_float2(re, im);
}

// ---------------------------------------------------------------------------
// K3: attention partials. block = (b, g, chunk of 256 kv rows), 512 thr = 8 waves.
// __launch_bounds__(512,4): 128-VGPR cap -> no spill (live state ~80 VGPR).
// ---------------------------------------------------------------------------
__global__ __launch_bounds__(512, 4) void attn_partial(
    const float* __restrict__ cache_k, const float* __restrict__ cache_v,
    const float* __restrict__ qkv, float* __restrict__ part) {
  __shared__ float qs[512];
  __shared__ float ss[4 * SS_STR];
  __shared__ float pacc[8][4][128];
  const int tid = threadIdx.x;
  const int w = tid >> 6, lane = tid & 63;
  const int p = lane >> 4, ql = lane & 15;
  const int chunk = blockIdx.x & 15;
  const int bg = blockIdx.x >> 4;
  const int b = bg >> 3, g = bg & 7;

  qs[tid] = qkv[b * QKV_COLS + g * 512 + tid];
  __syncthreads();

  // Q fragments: head h, d-range [ql*8, ql*8+8)
  float4 qA[4], qB[4];
#pragma unroll
  for (int h = 0; h < 4; ++h) {
    qA[h] = *(const float4*)(&qs[h * 128 + ql * 8]);
    qB[h] = *(const float4*)(&qs[h * 128 + ql * 8 + 4]);
  }

  const int t0 = chunk * CHUNK;
  const float* kbase = cache_k + ((size_t)b * 4096 * 8 + g) * 128;
  const float* xk    = qkv + b * QKV_COLS + 4096 + g * 128;

  // ---- scores ----
#pragma unroll 2
  for (int it = 0; it < 8; ++it) {
    int r = w * 32 + it * 4 + p;
    int t = t0 + r;
    const float* krow = (t == LASTPOS) ? xk : (kbase + (size_t)t * 1024);
    float4 k0 = *(const float4*)(krow + ql * 8);
    float4 k1 = *(const float4*)(krow + ql * 8 + 4);
    float s[4];
#pragma unroll
    for (int h = 0; h < 4; ++h) {
      s[h] = k0.x * qA[h].x + k0.y * qA[h].y + k0.z * qA[h].z + k0.w * qA[h].w
           + k1.x * qB[h].x + k1.y * qB[h].y + k1.z * qB[h].z + k1.w * qB[h].w;
    }
#pragma unroll
    for (int off = 1; off < 16; off <<= 1) {
#pragma unroll
      for (int h = 0; h < 4; ++h) s[h] += __shfl_xor(s[h], off);
    }
    float v = (ql == 0) ? s[0] : (ql == 1) ? s[1] : (ql == 2) ? s[2] : s[3];
    if (ql < 4) ss[ql * SS_STR + r] = v;
  }
  __syncthreads();

  // ---- chunk-local softmax, head = wave (waves 0-3) ----
  float* prow = part + ((size_t)(bg * NCH + chunk) * 4 + (w & 3)) * 130;
  if (w < 4) {
    float vals[4];
    float m = -1e30f;
#pragma unroll
    for (int i = 0; i < 4; ++i) {
      vals[i] = ss[w * SS_STR + lane + 64 * i];
      m = fmaxf(m, vals[i]);
    }
#pragma unroll
    for (int off = 1; off < 64; off <<= 1) m = fmaxf(m, __shfl_xor(m, off));
    float l = 0.f;
#pragma unroll
    for (int i = 0; i < 4; ++i) {
      float pe = __expf(vals[i] - m);
      ss[w * SS_STR + lane + 64 * i] = pe;
      l += pe;
    }
#pragma unroll
    for (int off = 1; off < 64; off <<= 1) l += __shfl_xor(l, off);
    if (lane == 0) { prow[128] = m; prow[129] = l; }
  }
  __syncthreads();

  // ---- PV: wave w covers rows [w*32, w*32+32), half-wave owns a row ----
  const float* vbase = cache_v + ((size_t)b * 4096 * 8 + g) * 128;
  const float* xv    = qkv + b * QKV_COLS + 5120 + g * 128;
  const int h2 = lane >> 5;
  const int dq = lane & 31;
  float4 acc[4];
#pragma unroll
  for (int h = 0; h < 4; ++h) acc[h] = make_float4(0.f, 0.f, 0.f, 0.f);

#pragma unroll 8
  for (int j = 0; j < 16; ++j) {
    int r = w * 32 + 2 * j + h2;
    int t = t0 + r;
    const float* vrow = (t == LASTPOS) ? xv : (vbase + (size_t)t * 1024);
    float4 vv = *(const float4*)(vrow + dq * 4);
    float p0 = ss[0 * SS_STR + r];
    float p1 = ss[1 * SS_STR + r];
    float p2 = ss[2 * SS_STR + r];
    float p3 = ss[3 * SS_STR + r];
    acc[0].x += p0 * vv.x; acc[0].y += p0 * vv.y; acc[0].z += p0 * vv.z; acc[0].w += p0 * vv.w;
    acc[1].x += p1 * vv.x; acc[1].y += p1 * vv.y; acc[1].z += p1 * vv.z; acc[1].w += p1 * vv.w;
    acc[2].x += p2 * vv.x; acc[2].y += p2 * vv.y; acc[2].z += p2 * vv.z; acc[2].w += p2 * vv.w;
    acc[3].x += p3 * vv.x; acc[3].y += p3 * vv.y; acc[3].z += p3 * vv.z; acc[3].w += p3 * vv.w;
  }
#pragma unroll
  for (int h = 0; h < 4; ++h) {
    acc[h].x += __shfl_xor(acc[h].x, 32);
    acc[h].y += __shfl_xor(acc[h].y, 32);
    acc[h].z += __shfl_xor(acc[h].z, 32);
    acc[h].w += __shfl_xor(acc[h].w, 32);
  }
  if (lane < 32) {
#pragma unroll
    for (int h = 0; h < 4; ++h)
      *(float4*)(&pacc[w][h][dq * 4]) = acc[h];
  }
  __syncthreads();

  // ---- cross-wave combine: 512 threads = 4 heads x 128 d ----
  {
    int h = tid >> 7, d = tid & 127;
    float sum = 0.f;
#pragma unroll
    for (int w2 = 0; w2 < 8; ++w2) sum += pacc[w2][h][d];
    part[((size_t)(bg * NCH + chunk) * 4 + h) * 130 + d] = sum;
  }
}

// ---------------------------------------------------------------------------
// K4: combine 16 chunk-partials per (b,g,r,d) -> attn_out[b][h][d]
// ---------------------------------------------------------------------------
__global__ __launch_bounds__(256) void attn_combine(
    const float* __restrict__ part, float* __restrict__ attn_out) {
  int t = blockIdx.x * 256 + threadIdx.x;  // 65536
  int d = t & 127, r = (t >> 7) & 3, bg = t >> 9;
  int b = bg >> 3, g = bg & 7;
  float M = -1e30f;
  float ms[NCH];
#pragma unroll
  for (int c = 0; c < NCH; ++c) {
    ms[c] = part[((size_t)(bg * NCH + c) * 4 + r) * 130 + 128];
    M = fmaxf(M, ms[c]);
  }
  float num = 0.f, den = 0.f;
#pragma unroll
  for (int c = 0; c < NCH; ++c) {
    const float* prow = part + ((size_t)(bg * NCH + c) * 4 + r) * 130;
    float wgt = __expf(ms[c] - M);
    num += wgt * prow[d];
    den += wgt * prow[129];
  }
  attn_out[b * DIM + (g * 4 + r) * 128 + d] = num / den;
}

// ---------------------------------------------------------------------------
// K5a: wo partials. block: 256 thr, 2 cols/thread (512 cols); grid (8, 64).
// ---------------------------------------------------------------------------
__global__ __launch_bounds__(256) void out_projA(
    const float* __restrict__ attn, const float* __restrict__ wo,
    float* __restrict__ pw) {
  __shared__ float xs[16 * 64];
  const int tid = threadIdx.x;
  const int col = (blockIdx.x * 256 + tid) * 2;  // 0..4094
  const int kc = blockIdx.y;
  const int k0 = kc * 64;

  for (int i = tid; i < 1024; i += 256) {
    int b = i >> 6, k = i & 63;
    xs[i] = attn[b * DIM + k0 + k];
  }
  __syncthreads();

  const float* wp = wo + (size_t)k0 * 4096 + col;
  float acc0[16], acc1[16];
#pragma unroll
  for (int b = 0; b < 16; ++b) { acc0[b] = 0.f; acc1[b] = 0.f; }

#pragma unroll 2
  for (int k = 0; k < 64; k += 4) {
    float2 w0 = *(const float2*)(wp + (size_t)(k + 0) * 4096);
    float2 w1 = *(const float2*)(wp + (size_t)(k + 1) * 4096);
    float2 w2 = *(const float2*)(wp + (size_t)(k + 2) * 4096);
    float2 w3 = *(const float2*)(wp + (size_t)(k + 3) * 4096);
#pragma unroll
    for (int b = 0; b < 16; ++b) {
      float4 xb = *(const float4*)(&xs[b * 64 + k]);
      acc0[b] += xb.x * w0.x + xb.y * w1.x + xb.z * w2.x + xb.w * w3.x;
      acc1[b] += xb.x * w0.y + xb.y * w1.y + xb.z * w2.y + xb.w * w3.y;
    }
  }
#pragma unroll
  for (int b = 0; b < 16; ++b) {
    *(float2*)(&pw[((size_t)kc * 16 + b) * DIM + col]) = make_float2(acc0[b], acc1[b]);
  }
}

// ---------------------------------------------------------------------------
// K5b: reduce 64 wo partials -> d_out.
// ---------------------------------------------------------------------------
__global__ __launch_bounds__(256) void out_projB(
    const float* __restrict__ pw, float* __restrict__ out) {
  int t = blockIdx.x * 256 + threadIdx.x;  // 65536
  int b = t >> 12, col = t & 4095;
  float sum = 0.f;
#pragma unroll 8
  for (int kc = 0; kc < NKC; ++kc)
    sum += pw[((size_t)kc * 16 + b) * DIM + col];
  out[b * DIM + col] = sum;
}

// ---------------------------------------------------------------------------
extern "C" void kernel_launch(void* const* d_in, const int* in_sizes, int n_in,
                              void* d_out, int out_size, void* d_ws, size_t ws_size,
                              hipStream_t stream) {
  const float* x  = (const float*)d_in[0];
  const float* wq = (const float*)d_in[1];
  const float* wk = (const float*)d_in[2];
  const float* wv = (const float*)d_in[3];
  const float* wo = (const float*)d_in[4];
  const float* ck = (const float*)d_in[5];
  const float* cv = (const float*)d_in[6];
  const float* fc = (const float*)d_in[7];
  const float* fs = (const float*)d_in[8];

  float* ws_f  = (float*)d_ws;
  float* qkv   = ws_f + WS_QKV;
  float* attn  = ws_f + WS_ATTN;
  float* part  = ws_f + WS_PART;
  float* pq    = ws_f + WS_PQ;
  float* pw    = ws_f + WS_PW;
  float* out   = (float*)d_out;

  qkv_projA<<<dim3(12, NKC), 256, 0, stream>>>(x, wq, wk, wv, pq);
  qkv_projB<<<192, 256, 0, stream>>>(pq, qkv, fc, fs);
  attn_partial<<<2048, 512, 0, stream>>>(ck, cv, qkv, part);
  attn_combine<<<256, 256, 0, stream>>>(part, attn);
  out_projA<<<dim3(8, NKC), 256, 0, stream>>>(attn, wo, pw);
  out_projB<<<256, 256, 0, stream>>>(pw, out);
}